// Round 1
// baseline (897.386 us; speedup 1.0000x reference)
//
#include <hip/hip_runtime.h>
#include <cstdint>

// Problem: y = x @ dequant(peso, escala)^T
//   x:      [M=4096, K=4096]  f32  (B=2, S=2048 flattened)
//   peso:   [N=12288, K=4096] f32
//   escala: [N/128, K/128]    f32
//   y:      [M, N]            f32
// Strategy: prepass-convert both operands to bf16 in d_ws (dequant fused into
// the weight conversion), then run the m97-structure bf16 MFMA GEMM.

#define TM 128   // tile M and N
#define BK 32    // K-slice per iteration (one 16x16x32 MFMA K-step)

typedef __bf16 bf16x8 __attribute__((ext_vector_type(8)));
typedef float  f32x4  __attribute__((ext_vector_type(4)));

__device__ __forceinline__ ushort f32_to_bf16_rne(float f) {
    union { float f; uint32_t u; } v; v.f = f;
    uint32_t u = v.u;
    return (ushort)((u + 0x7FFFu + ((u >> 16) & 1u)) >> 16);
}

__device__ __forceinline__ void async16(const ushort* g, ushort* l) {
    // global -> LDS direct copy, 16 B/lane; LDS dest = wave-uniform base + lane*16
    __builtin_amdgcn_global_load_lds(
        (const __attribute__((address_space(1))) void*)g,
        (__attribute__((address_space(3))) void*)l,
        16, 0, 0);
}

// ---------------- prepass 1: x f32 -> bf16 ----------------
__global__ void convert_x_kernel(const float* __restrict__ x,
                                 ushort* __restrict__ xb, int n4) {
    int t = blockIdx.x * blockDim.x + threadIdx.x;
    if (t >= n4) return;
    float4 v = ((const float4*)x)[t];
    ushort4 o;
    o.x = f32_to_bf16_rne(v.x);
    o.y = f32_to_bf16_rne(v.y);
    o.z = f32_to_bf16_rne(v.z);
    o.w = f32_to_bf16_rne(v.w);
    ((ushort4*)xb)[t] = o;
}

// ---------------- prepass 2: W = peso * escala, f32 -> bf16 ----------------
// Hardcoded K=4096 (shifts); a float4 never crosses a 128-wide scale block.
__global__ void dequant_w_kernel(const float* __restrict__ w,
                                 const float* __restrict__ s,
                                 ushort* __restrict__ wb, int n4) {
    int t = blockIdx.x * blockDim.x + threadIdx.x;
    if (t >= n4) return;
    int e = t << 2;                 // element index, < 2^26 fits int
    int o = e >> 12;                // / 4096
    int i = e & 4095;
    float sc = s[(o >> 7) * 32 + (i >> 7)];
    float4 v = ((const float4*)w)[t];
    ushort4 u;
    u.x = f32_to_bf16_rne(v.x * sc);
    u.y = f32_to_bf16_rne(v.y * sc);
    u.z = f32_to_bf16_rne(v.z * sc);
    u.w = f32_to_bf16_rne(v.w * sc);
    ((ushort4*)wb)[t] = u;
}

// ---------------- main GEMM: C[M,N] = A[M,K] @ B[N,K]^T (both bf16, K-major) ----------------
__global__ __launch_bounds__(256) void gemm_bf16_bt(
    const ushort* __restrict__ A,   // [M][K] bf16 bits
    const ushort* __restrict__ B,   // [N][K] bf16 bits
    float* __restrict__ C,          // [M][N] f32
    int M, int N, int K)
{
    __shared__ __align__(16) ushort lA[TM * BK];  // 8 KB, row-major [row][k]
    __shared__ __align__(16) ushort lB[TM * BK];  // 8 KB

    const int tid  = threadIdx.x;
    const int wave = tid >> 6;         // 0..3
    const int lane = tid & 63;
    const int m0 = blockIdx.y * TM;
    const int n0 = blockIdx.x * TM;

    const int wm   = (wave >> 1) * 64; // wave's M offset in tile
    const int wn   = (wave & 1) * 64;  // wave's N offset in tile
    const int quad = lane >> 4;        // 0..3
    const int l15  = lane & 15;

    // staging geometry: 1024-B chunk per wave per instr = 16 rows x 64 B
    const int r4 = lane >> 2;          // row within chunk (0..15)
    const int c4 = (lane & 3) * 8;     // k-element offset (0/8/16/24)

    const ushort* ga0 = A + (size_t)(m0 +      wave * 16 + r4) * K + c4;
    const ushort* ga1 = A + (size_t)(m0 + 64 + wave * 16 + r4) * K + c4;
    const ushort* gb0 = B + (size_t)(n0 +      wave * 16 + r4) * K + c4;
    const ushort* gb1 = B + (size_t)(n0 + 64 + wave * 16 + r4) * K + c4;

    ushort* sa0 = lA + wave * 512;          // chunk `wave`
    ushort* sa1 = lA + (wave + 4) * 512;    // chunk `wave+4`
    ushort* sb0 = lB + wave * 512;
    ushort* sb1 = lB + (wave + 4) * 512;

    f32x4 acc[4][4];
    #pragma unroll
    for (int i = 0; i < 4; ++i)
        #pragma unroll
        for (int j = 0; j < 4; ++j)
            acc[i][j] = f32x4{0.f, 0.f, 0.f, 0.f};

    // fragment read base: A[m=lane&15][k=quad*8+j]
    const ushort* pA = lA + (wm + l15) * BK + quad * 8;
    const ushort* pB = lB + (wn + l15) * BK + quad * 8;

    for (int kk = 0; kk < K; kk += BK) {
        async16(ga0 + kk, sa0);
        async16(ga1 + kk, sa1);
        async16(gb0 + kk, sb0);
        async16(gb1 + kk, sb1);
        __syncthreads();   // emits s_waitcnt vmcnt(0) before s_barrier

        bf16x8 af[4], bfr[4];
        #pragma unroll
        for (int i = 0; i < 4; ++i) af[i]  = *(const bf16x8*)(pA + i * 16 * BK);
        #pragma unroll
        for (int j = 0; j < 4; ++j) bfr[j] = *(const bf16x8*)(pB + j * 16 * BK);

        #pragma unroll
        for (int i = 0; i < 4; ++i)
            #pragma unroll
            for (int j = 0; j < 4; ++j)
                acc[i][j] = __builtin_amdgcn_mfma_f32_16x16x32_bf16(
                    af[i], bfr[j], acc[i][j], 0, 0, 0);

        __syncthreads();   // protect LDS before next stage overwrites
    }

    // epilogue: D layout col=lane&15, row=quad*4+reg (m89-verified)
    #pragma unroll
    for (int i = 0; i < 4; ++i) {
        const int row0 = m0 + wm + i * 16 + quad * 4;
        #pragma unroll
        for (int j = 0; j < 4; ++j) {
            const int col = n0 + wn + j * 16 + l15;
            #pragma unroll
            for (int r = 0; r < 4; ++r)
                C[(size_t)(row0 + r) * N + col] = acc[i][j][r];
        }
    }
}

// ---------------- emergency fallback (ws too small): correct but slow ----------------
__global__ void fallback_kernel(const float* __restrict__ x,
                                const float* __restrict__ w,
                                const float* __restrict__ s,
                                float* __restrict__ y,
                                int M, int N, int K) {
    long long idx = (long long)blockIdx.x * blockDim.x + threadIdx.x;
    if (idx >= (long long)M * N) return;
    int m = (int)(idx / N), n = (int)(idx % N);
    const float* xr = x + (size_t)m * K;
    const float* wr = w + (size_t)n * K;
    const float* sr = s + (size_t)(n >> 7) * (K >> 7);
    float acc = 0.f;
    for (int k = 0; k < K; ++k)
        acc += xr[k] * wr[k] * sr[k >> 7];
    y[idx] = acc;
}

extern "C" void kernel_launch(void* const* d_in, const int* in_sizes, int n_in,
                              void* d_out, int out_size, void* d_ws, size_t ws_size,
                              hipStream_t stream) {
    const float* x      = (const float*)d_in[0];
    const float* peso   = (const float*)d_in[1];
    const float* escala = (const float*)d_in[2];
    float* y = (float*)d_out;

    const int K = 4096;
    const int N = 12288;
    const int M = in_sizes[0] / K;   // 4096

    const size_t xb_elems = (size_t)M * K;
    const size_t wb_elems = (size_t)N * K;
    const size_t need = (xb_elems + wb_elems) * sizeof(ushort);  // 128 MB

    if (ws_size >= need) {
        ushort* xb = (ushort*)d_ws;
        ushort* wb = xb + xb_elems;

        const int nx4 = (int)(xb_elems / 4);
        convert_x_kernel<<<(nx4 + 255) / 256, 256, 0, stream>>>(x, xb, nx4);

        const int nw4 = (int)(wb_elems / 4);
        dequant_w_kernel<<<(nw4 + 255) / 256, 256, 0, stream>>>(peso, escala, wb, nw4);

        dim3 grid(N / TM, M / TM);   // (96, 32)
        gemm_bf16_bt<<<grid, 256, 0, stream>>>(xb, wb, y, M, N, K);
    } else {
        long long total = (long long)M * N;
        int blocks = (int)((total + 255) / 256);
        fallback_kernel<<<blocks, 256, 0, stream>>>(x, peso, escala, y, M, N, K);
    }
}